// Round 2
// baseline (89.696 us; speedup 1.0000x reference)
//
#include <hip/hip_runtime.h>

#define DD 128
#define KADJ 12
#define BN_TOTAL 12800

typedef float f32x4 __attribute__((ext_vector_type(4)));
typedef __bf16 bf16x8 __attribute__((ext_vector_type(8)));

__device__ __forceinline__ bf16x8 cvt8(f32x4 a, f32x4 b) {
    bf16x8 r;
    r[0] = (__bf16)a[0]; r[1] = (__bf16)a[1]; r[2] = (__bf16)a[2]; r[3] = (__bf16)a[3];
    r[4] = (__bf16)b[0]; r[5] = (__bf16)b[1]; r[6] = (__bf16)b[2]; r[7] = (__bf16)b[3];
    return r;
}

// ---- K0: w1[0:128][128] -> w1t[d][k] bf16 (32KB); w3[256][128] -> w3t[d][c] bf16 (64KB)
__global__ void k_prep(const float* __restrict__ w1, const float* __restrict__ w3,
                       __bf16* __restrict__ w1t, __bf16* __restrict__ w3t) {
    int b = blockIdx.x, t = threadIdx.x;
    if (b < 64) {
        int d = b * 2 + (t >> 7), k = t & 127;
        w1t[d * 128 + k] = (__bf16)w1[k * 128 + d];
    } else {
        int d = b - 64, c = t;
        w3t[d * 256 + c] = (__bf16)w3[c * 128 + d];
    }
}

// ---- K1: per (b,n) in one wave, no LDS, no barriers ----
__launch_bounds__(256, 4)
__global__ void k_att(const float* __restrict__ ave, const float* __restrict__ adj,
                      const float* __restrict__ wgt, const float* __restrict__ w1,
                      const float* __restrict__ w2, const __bf16* __restrict__ w1t,
                      float* __restrict__ att_out) {
    const int t = threadIdx.x;
    const int lane = t & 63;
    const int w = t >> 6;
    const int bn = blockIdx.x * 4 + w;
    const int l = lane & 15, g = lane >> 4;

    // --- A-frags + adj kept in bf16 regs. A[r][c] = ave[c]*adj[r][c], c<128.
    const float* avep = ave + (size_t)bn * DD;
    const float* adjp = adj + (size_t)bn * KADJ * DD + (size_t)min(l, KADJ - 1) * DD;
    const bool rowok = (l < KADJ);
    bf16x8 af[4], ubf[4];
    #pragma unroll
    for (int s = 0; s < 4; ++s) {
        int c = s * 32 + g * 8;
        f32x4 u0 = *reinterpret_cast<const f32x4*>(adjp + c);
        f32x4 u1 = *reinterpret_cast<const f32x4*>(adjp + c + 4);
        f32x4 e0 = *reinterpret_cast<const f32x4*>(avep + c);
        f32x4 e1 = *reinterpret_cast<const f32x4*>(avep + c + 4);
        if (!rowok) { u0 = f32x4{0.f,0.f,0.f,0.f}; u1 = f32x4{0.f,0.f,0.f,0.f}; }
        ubf[s] = cvt8(u0, u1);
        af[s]  = cvt8(u0 * e0, u1 * e1);
    }

    // rank-1 (wgt column) + w2 operands, fp32
    float w1r[8], w2v[8];
    #pragma unroll
    for (int n = 0; n < 8; ++n) {
        w1r[n] = w1[128 * DD + n * 16 + l];   // w1 row 128 (the concat'd wgt row)
        w2v[n] = w2[n * 16 + l];
    }
    float wgtv[4];
    #pragma unroll
    for (int j = 0; j < 4; ++j) {
        int r = g * 4 + j;
        wgtv[j] = (r < KADJ) ? wgt[(size_t)bn * KADJ + r] : 0.f;
    }

    // --- MFMA: C[16x128] = A @ w1t^T, B-frags straight from L1-resident w1t
    f32x4 acc[8];
    #pragma unroll
    for (int n = 0; n < 8; ++n) acc[n] = f32x4{0.f,0.f,0.f,0.f};
    #pragma unroll
    for (int s = 0; s < 4; ++s) {
        const __bf16* bp = w1t + (size_t)l * 128 + s * 32 + g * 8;
        #pragma unroll
        for (int n = 0; n < 8; ++n) {
            bf16x8 bfr = *reinterpret_cast<const bf16x8*>(bp + n * 2048);
            acc[n] = __builtin_amdgcn_mfma_f32_16x16x32_bf16(af[s], bfr, acc[n], 0, 0, 0);
        }
    }

    // --- epilogue: rank-1 add, leaky, dot w2. acc[n][j] = h[row g*4+j][col n*16+l]
    float p[4] = {0.f, 0.f, 0.f, 0.f};
    #pragma unroll
    for (int n = 0; n < 8; ++n) {
        #pragma unroll
        for (int j = 0; j < 4; ++j) {
            float h = fmaf(wgtv[j], w1r[n], acc[n][j]);
            h = h > 0.f ? h : 0.2f * h;
            p[j] = fmaf(h, w2v[n], p[j]);
        }
    }
    #pragma unroll
    for (int j = 0; j < 4; ++j) {
        p[j] += __shfl_xor(p[j], 1, 64);
        p[j] += __shfl_xor(p[j], 2, 64);
        p[j] += __shfl_xor(p[j], 4, 64);
        p[j] += __shfl_xor(p[j], 8, 64);
        if (g * 4 + j >= KADJ) p[j] = -1e30f;   // exclude pad rows from softmax
    }

    // gather all 16 scores (rows 4(g^m)+j), softmax stats over the 12 real ones
    float q0[4], q1[4], q2[4];
    #pragma unroll
    for (int j = 0; j < 4; ++j) {
        q0[j] = __shfl_xor(p[j], 16, 64);
        q1[j] = __shfl_xor(p[j], 32, 64);
        q2[j] = __shfl_xor(q1[j], 16, 64);
    }
    float mx = p[0];
    #pragma unroll
    for (int j = 0; j < 4; ++j) {
        mx = fmaxf(mx, p[j]); mx = fmaxf(mx, q0[j]);
        mx = fmaxf(mx, q1[j]); mx = fmaxf(mx, q2[j]);
    }
    float ssum = 0.f;
    #pragma unroll
    for (int j = 0; j < 4; ++j) {
        ssum += __expf(p[j] - mx);  ssum += __expf(q0[j] - mx);
        ssum += __expf(q1[j] - mx); ssum += __expf(q2[j] - mx);
    }

    // this lane's own alpha (row l): fetch s[l] from the lane group holding it
    int srcl = (l >> 2) << 4;
    float c0 = __shfl(p[0], srcl, 64);
    float c1 = __shfl(p[1], srcl, 64);
    float c2 = __shfl(p[2], srcl, 64);
    float c3 = __shfl(p[3], srcl, 64);
    int jm = l & 3;
    float sl = jm == 0 ? c0 : jm == 1 ? c1 : jm == 2 ? c2 : c3;
    float alphal = __expf(sl - mx) / ssum;   // rows >=12 -> 0

    // --- att[c] = sum_l alpha[l]*adj[l][c]; reduce over l-lanes, store fp32 to d_out
    #pragma unroll
    for (int s = 0; s < 4; ++s) {
        float q[8];
        #pragma unroll
        for (int j2 = 0; j2 < 8; ++j2) q[j2] = alphal * (float)ubf[s][j2];
        #pragma unroll
        for (int j2 = 0; j2 < 8; ++j2) {
            q[j2] += __shfl_xor(q[j2], 1, 64);
            q[j2] += __shfl_xor(q[j2], 2, 64);
            q[j2] += __shfl_xor(q[j2], 4, 64);
            q[j2] += __shfl_xor(q[j2], 8, 64);
        }
        if (l == s) {
            float* op = att_out + (size_t)bn * DD + s * 32 + g * 8;
            *reinterpret_cast<f32x4*>(op)     = f32x4{q[0], q[1], q[2], q[3]};
            *reinterpret_cast<f32x4*>(op + 4) = f32x4{q[4], q[5], q[6], q[7]};
        }
    }
}

// ---- K2: out = relu([itm | att] @ w3) via MFMA; att read from own rows of d_out ----
__launch_bounds__(64)
__global__ void k_out(const float* __restrict__ itm, const float* att,
                      const __bf16* __restrict__ w3t, float* outp) {
    const int lane = threadIdx.x & 63;
    const int l = lane & 15, g = lane >> 4;
    const int R0 = blockIdx.x * 16;
    const int row = R0 + l;

    bf16x8 afr[8];
    const float* ip = itm + (size_t)row * DD;
    #pragma unroll
    for (int s = 0; s < 4; ++s) {
        int c = s * 32 + g * 8;
        f32x4 a0 = *reinterpret_cast<const f32x4*>(ip + c);
        f32x4 a1 = *reinterpret_cast<const f32x4*>(ip + c + 4);
        afr[s] = cvt8(a0, a1);
    }
    const float* ap = att + (size_t)row * DD;
    #pragma unroll
    for (int s = 0; s < 4; ++s) {
        int c = s * 32 + g * 8;
        f32x4 a0 = *reinterpret_cast<const f32x4*>(ap + c);
        f32x4 a1 = *reinterpret_cast<const f32x4*>(ap + c + 4);
        afr[4 + s] = cvt8(a0, a1);
    }

    f32x4 acc[8];
    #pragma unroll
    for (int n = 0; n < 8; ++n) acc[n] = f32x4{0.f,0.f,0.f,0.f};
    #pragma unroll
    for (int s = 0; s < 8; ++s) {
        const __bf16* bp = w3t + (size_t)l * 256 + s * 32 + g * 8;
        #pragma unroll
        for (int n = 0; n < 8; ++n) {
            bf16x8 bfr = *reinterpret_cast<const bf16x8*>(bp + n * 4096);
            acc[n] = __builtin_amdgcn_mfma_f32_16x16x32_bf16(afr[s], bfr, acc[n], 0, 0, 0);
        }
    }

    #pragma unroll
    for (int n = 0; n < 8; ++n) {
        #pragma unroll
        for (int j = 0; j < 4; ++j)
            outp[(size_t)(R0 + g * 4 + j) * DD + n * 16 + l] = fmaxf(acc[n][j], 0.f);
    }
}

extern "C" void kernel_launch(void* const* d_in, const int* in_sizes, int n_in,
                              void* d_out, int out_size, void* d_ws, size_t ws_size,
                              hipStream_t stream) {
    const float* itm = (const float*)d_in[1];
    const float* ave = (const float*)d_in[2];
    const float* adj = (const float*)d_in[3];
    const float* wgt = (const float*)d_in[4];
    const float* w1  = (const float*)d_in[5];
    const float* w2  = (const float*)d_in[6];
    const float* w3  = (const float*)d_in[7];
    float* outp = (float*)d_out;

    __bf16* w1t = (__bf16*)d_ws;                       // 128*128*2 = 32 KB
    __bf16* w3t = (__bf16*)((char*)d_ws + 32 * 1024);  // 128*256*2 = 64 KB

    k_prep<<<dim3(192), dim3(256), 0, stream>>>(w1, w3, w1t, w3t);
    k_att<<<dim3(BN_TOTAL / 4), dim3(256), 0, stream>>>(ave, adj, wgt, w1, w2, w1t, outp);
    k_out<<<dim3(BN_TOTAL / 16), dim3(64), 0, stream>>>(itm, outp, w3t, outp);
}